// Round 7
// baseline (353.977 us; speedup 1.0000x reference)
//
#include <hip/hip_runtime.h>
#include <stdint.h>

typedef unsigned short u16;
typedef __attribute__((ext_vector_type(8))) short bf16x8;
typedef __attribute__((ext_vector_type(4))) float f32x4;

#define MFMA16(a, b, c) __builtin_amdgcn_mfma_f32_16x16x32_bf16(a, b, c, 0, 0, 0)

__device__ __forceinline__ u16 f2bf(float x) {
  union { float f; uint32_t u; } v; v.f = x;
  uint32_t r = (v.u + 0x7FFFu + ((v.u >> 16) & 1u)) >> 16;
  return (u16)r;
}
__device__ __forceinline__ float bf2f(u16 h) {
  union { uint32_t u; float f; } v; v.u = ((uint32_t)h) << 16; return v.f;
}
// packed RNE f32x2 -> bf16x2 (gfx942+ VOP3; low16 = a, high16 = b)
__device__ __forceinline__ uint cvt_pk_bf16(float a, float b) {
  uint r;
  asm("v_cvt_pk_bf16_f32 %0, %1, %2" : "=v"(r) : "v"(a), "v"(b));
  return r;
}
__device__ __forceinline__ void gll16(const void* g, void* s) {
  __builtin_amdgcn_global_load_lds((const __attribute__((address_space(1))) unsigned int*)g,
                                   (__attribute__((address_space(3))) unsigned int*)s, 16, 0, 0);
}

// ---------------- pack kernels ----------------

// grid (6000,1,3), block 256: fp32 -> bf16, 4 elems/thread
__global__ __launch_bounds__(256) void pack_x_kernel(const float* __restrict__ q,
                                                     const float* __restrict__ k,
                                                     const float* __restrict__ v,
                                                     u16* __restrict__ X) {
  const float* src = blockIdx.z == 0 ? q : (blockIdx.z == 1 ? k : v);
  u16* dst = X + (size_t)blockIdx.z * (6016UL * 1024UL);
  size_t idx = (size_t)blockIdx.x * 1024 + (size_t)threadIdx.x * 4;
  float4 f = *(const float4*)(src + idx);
  uint2 o;
  o.x = cvt_pk_bf16(f.x, f.y);
  o.y = cvt_pk_bf16(f.z, f.w);
  *(uint2*)(dst + idx) = o;
}

// merged weight/misc pack, grid 1025 blocks:
//  [0,768):    Wt[z][(n*64+d)*1024 + h] = W[z][n][h][d]
//  [768,1024): Wfct[o*1024 + i] = Wfc[i*1024 + o]
//  1024:       bias concat + pos_k bf16 (144 rows) + pos_v^T bf16 (64x136)
__global__ __launch_bounds__(256) void pack_w_kernel(const float* __restrict__ Wq,
                                                     const float* __restrict__ Wk,
                                                     const float* __restrict__ Wv,
                                                     const float* __restrict__ Wfc,
                                                     const float* __restrict__ bq,
                                                     const float* __restrict__ bk,
                                                     const float* __restrict__ bv,
                                                     const float* __restrict__ posk,
                                                     const float* __restrict__ posv,
                                                     u16* __restrict__ Wt,
                                                     u16* __restrict__ Wfct,
                                                     float* __restrict__ biascat,
                                                     u16* __restrict__ poskbf,
                                                     u16* __restrict__ posvT) {
  __shared__ float tile[64][65];
  const int bi = blockIdx.x;
  if (bi == 1024) {
    for (int i = threadIdx.x; i < 1024; i += 256) {
      biascat[i] = bq[i]; biascat[1024 + i] = bk[i]; biascat[2048 + i] = bv[i];
    }
    for (int i = threadIdx.x; i < 144 * 64; i += 256) {
      int r = i >> 6;
      poskbf[i] = (r < 129) ? f2bf(posk[i]) : (u16)0;
    }
    const int d = threadIdx.x & 63, rr = threadIdx.x >> 6;
#pragma unroll
    for (int j = 0; j < 34; ++j) {
      const int r = rr * 34 + j;
      posvT[d * 136 + r] = (r < 129) ? f2bf(posv[(size_t)r * 64 + d]) : (u16)0;
    }
    return;
  }
  const int r = threadIdx.x >> 2, c0 = (threadIdx.x & 3) * 16;
  const float* src;
  u16* outp;
  if (bi < 768) {
    const int z = bi >> 8, rem = bi & 255, n = rem >> 4, h0 = (rem & 15) * 64;
    const float* W = z == 0 ? Wq : (z == 1 ? Wk : Wv);
    src = W + (size_t)n * 65536 + (size_t)(h0 + r) * 64 + c0;
    outp = Wt + (size_t)z * (1024UL * 1024UL) + (size_t)(n * 64 + r) * 1024 + h0 + c0;
  } else {
    const int t = bi - 768;
    const int i0 = (t & 15) * 64, o0 = (t >> 4) * 64;
    src = Wfc + (size_t)(i0 + r) * 1024 + o0 + c0;
    outp = Wfct + (size_t)(o0 + r) * 1024 + i0 + c0;
  }
#pragma unroll
  for (int j = 0; j < 16; j += 4) {
    float4 f = *(const float4*)(src + j);
    tile[r][c0 + j] = f.x; tile[r][c0 + j + 1] = f.y;
    tile[r][c0 + j + 2] = f.z; tile[r][c0 + j + 3] = f.w;
  }
  __syncthreads();
#pragma unroll
  for (int j = 0; j < 16; ++j) outp[j] = f2bf(tile[c0 + j][r]);
}

// grid (1536) 1-D, XCD-swizzled: bh = bi&63 (XCD = bh%8), s-tile = bi>>6.
// transpose V [bh][1536][64] -> Vt [bh][64][1536]
__global__ __launch_bounds__(256) void vtrans_kernel(const u16* __restrict__ qkv,
                                                     u16* __restrict__ Vt) {
  const size_t ZS = 4UL * 16 * 1536 * 64;
  __shared__ u16 t[64][72];
  const int bh = blockIdx.x & 63, s0 = (blockIdx.x >> 6) * 64;
  const u16* src = qkv + 2 * ZS + (size_t)bh * (1536UL * 64UL) + (size_t)s0 * 64;
  const int r = threadIdx.x >> 2, c0 = (threadIdx.x & 3) * 16;
  *(uint4*)&t[r][c0]     = *(const uint4*)(src + (size_t)r * 64 + c0);
  *(uint4*)&t[r][c0 + 8] = *(const uint4*)(src + (size_t)r * 64 + c0 + 8);
  __syncthreads();
  uint4 a, bvec;
  uint tmp[8];
#pragma unroll
  for (int j = 0; j < 8; ++j)
    tmp[j] = (uint)t[c0 + 2 * j][r] | ((uint)t[c0 + 2 * j + 1][r] << 16);
  a.x = tmp[0]; a.y = tmp[1]; a.z = tmp[2]; a.w = tmp[3];
  bvec.x = tmp[4]; bvec.y = tmp[5]; bvec.z = tmp[6]; bvec.w = tmp[7];
  u16* dst = Vt + (size_t)(bh * 64 + r) * 1536 + s0 + c0;
  *(uint4*)dst = a;
  *(uint4*)(dst + 8) = bvec;
}

// ---------------- GEMM v13: C[m,n] = sum_k A[m,k]*Bt[n,k] (+bias) ----------------
// Changes vs v12's m97-style loop:
//  (1) depth-1 LDS double-buffer: per iter {vmcnt(0); s_barrier; stage(kt+1 -> other
//      buf); compute(kt)} -- DMA of kt+1 overlaps compute of kt; 1 barrier/iter (was 2,
//      zero overlap). Write-hazard safe: stage targets the buffer last read at kt-1 and
//      all waves passed this iter's barrier only after finishing kt-1's compute.
//  (2) bijective XCD swizzle of the linear block id (nwg = 1128 / 376, both %8==0):
//      each XCD gets a contiguous tile chunk -> A-panel reuse in its private L2.
// LDS 16->32 KB (still 4 blocks/CU: VGPR-bound). Epilogues unchanged.
__global__ __launch_bounds__(256, 4) void gemm_bt_kernel(
    const u16* __restrict__ Abase, long aStride,
    const u16* __restrict__ Bbase, long bStride,
    const float* __restrict__ biasBase, long biasStride,
    u16* __restrict__ outBF, float* __restrict__ outF, int mode) {
  __shared__ u16 As[2][128 * 32];
  __shared__ u16 Bs[2][128 * 32];

  // XCD-aware bijective swizzle of the 3D grid (x=8 n-tiles fastest, y=47 m, z)
  const int nwg = 376 * gridDim.z;           // 1128 (qkv) or 376 (fc)
  const int cpx = nwg >> 3;
  const int lid = blockIdx.x + (blockIdx.y << 3) + blockIdx.z * 376;
  const int swz = (lid & 7) * cpx + (lid >> 3);
  const int z = swz / 376;
  const int rem = swz - z * 376;
  const int m0 = (rem >> 3) * 128, n0 = (rem & 7) * 128;

  const u16* A = Abase + (size_t)z * aStride;
  const u16* Bt = Bbase + (size_t)z * bStride;
  const float* bias = biasBase + (size_t)z * biasStride;
  const int tid = threadIdx.x, w = tid >> 6, lane = tid & 63;
  const int quad = lane >> 4, l16 = lane & 15;
  const int wm = w >> 1, wn = w & 1;
  const int srow = w * 16 + (lane >> 2);
  const int scol = (lane & 3) * 8;
  // induction source pointers (advance +32 u16 per k-tile)
  const u16* gA = A + (size_t)(m0 + srow) * 1024 + scol;
  const u16* gB = Bt + (size_t)(n0 + srow) * 1024 + scol;
  const int lo0 = (w * 16) * 32;             // wave's LDS slab (low 64 rows)
  const int lo1 = (64 + w * 16) * 32;        // (high 64 rows)

  f32x4 acc[4][4];
  const f32x4 zf = {0.f, 0.f, 0.f, 0.f};
#pragma unroll
  for (int a = 0; a < 4; ++a)
#pragma unroll
    for (int b = 0; b < 4; ++b) acc[a][b] = zf;

  // stage tile from current gA/gB into buf, then advance cursors
  auto stage = [&](int buf) {
    gll16(gA, &As[buf][lo0]);
    gll16(gA + 64 * 1024, &As[buf][lo1]);
    gll16(gB, &Bs[buf][lo0]);
    gll16(gB + 64 * 1024, &Bs[buf][lo1]);
    gA += 32; gB += 32;
  };
  auto compute = [&](int buf) {
    bf16x8 af[4], bfr[4];
#pragma unroll
    for (int f = 0; f < 4; ++f) {
      af[f]  = *(const bf16x8*)(&As[buf][(wm * 64 + f * 16 + l16) * 32 + quad * 8]);
      bfr[f] = *(const bf16x8*)(&Bs[buf][(wn * 64 + f * 16 + l16) * 32 + quad * 8]);
    }
#pragma unroll
    for (int fm = 0; fm < 4; ++fm)
#pragma unroll
      for (int fn = 0; fn < 4; ++fn)
        acc[fm][fn] = MFMA16(af[fm], bfr[fn], acc[fm][fn]);
  };

  stage(0);   // prologue: tile 0 in flight

#define GEMM_WAIT_BAR() do {                                  \
    asm volatile("s_waitcnt vmcnt(0)" ::: "memory");          \
    __builtin_amdgcn_sched_barrier(0);                        \
    __builtin_amdgcn_s_barrier();                             \
    __builtin_amdgcn_sched_barrier(0);                        \
  } while (0)

#pragma unroll 1
  for (int pr = 0; pr < 16; ++pr) {
    // kt = 2pr (buf0 current)
    GEMM_WAIT_BAR();
    stage(1);                 // tile kt+1 -> buf1, overlaps compute(kt)
    compute(0);
    // kt = 2pr+1 (buf1 current)
    GEMM_WAIT_BAR();
    if (pr < 15) stage(0);    // tile kt+2 -> buf0
    compute(1);
  }
#undef GEMM_WAIT_BAR

  if (mode == 0) {
    const float scale = (z == 0) ? 0.125f : 1.0f;
    u16* out = outBF + (size_t)z * (4UL * 16 * 1536 * 64);
#pragma unroll
    for (int fm = 0; fm < 4; ++fm) {
#pragma unroll
      for (int i = 0; i < 4; ++i) {
        const int m = m0 + wm * 64 + fm * 16 + quad * 4 + i;
        if (m >= 6000) continue;
        const int bb = m / 1500;
        const int s = m - bb * 1500;
#pragma unroll
        for (int fn = 0; fn < 4; ++fn) {
          const int n = n0 + wn * 64 + fn * 16 + l16;
          const float vv = (acc[fm][fn][i] + bias[n]) * scale;
          const int h = n >> 6, d = n & 63;
          out[((size_t)(bb * 16 + h) * 1536 + s) * 64 + d] = f2bf(vv);
        }
      }
    }
  } else {
#pragma unroll
    for (int fm = 0; fm < 4; ++fm) {
#pragma unroll
      for (int i = 0; i < 4; ++i) {
        const int m = m0 + wm * 64 + fm * 16 + quad * 4 + i;
        if (m >= 6000) continue;
#pragma unroll
        for (int fn = 0; fn < 4; ++fn) {
          const int n = n0 + wn * 64 + fn * 16 + l16;
          outF[(size_t)m * 1024 + n] = acc[fm][fn][i] + bias[n];
        }
      }
    }
  }
}

// ---------------- fused attention v12: v11 + reg-budget + static addressing ----------
// (unchanged from round 6 -- 89.6 us, merged qp/pb buffer, permuted-K zero-shuffle PV,
//  static dbuf addressing via x2 unroll, induction staging pointers)
__global__ __launch_bounds__(256, 4) void attn_kernel(const u16* __restrict__ qkv,
                                                      const u16* __restrict__ Vt,
                                                      const u16* __restrict__ poskbf,
                                                      const u16* __restrict__ posvT,
                                                      const float* __restrict__ posv,
                                                      u16* __restrict__ hidden) {
  const size_t ZS = 4UL * 16 * 1536 * 64;
  __shared__ u16 qb_s[64 * 136];    // merged: qp[q][r] (prologue) -> P histogram [q][delta]
  __shared__ u16 kbuf[2][2048];     // K tile 32 rows x 64 d (row-permuted + chunk-swizzled), dbuf
  __shared__ u16 vbuf[2][2048];     // V^T tile 64 d x 32 k (chunk-swizzled), dbuf

  const int tid = threadIdx.x;
  const int w = tid >> 6, lane = tid & 63, quad = lane >> 4, l16 = lane & 15;
  const int bi = blockIdx.x;
  const int bh = bi & 63;
  const int q0 = (bi >> 6) * 64, qw0 = q0 + w * 16;
  const int b = bh >> 4;
  const size_t sb = (size_t)bh * (1536UL * 64UL);
  const u16* Qp = qkv + sb;
  const u16* Kp = qkv + ZS + sb;
  const u16* Vtb = Vt + (size_t)bh * (64UL * 1536UL);
  u16* qb_row = qb_s + (w * 16 + l16) * 136;   // this lane's row (q = qw0 + l16)

  // staging: wave-uniform LDS base + lane*16B (gll16 contract)
  const int r8 = lane >> 3, c8 = lane & 7;            // K: 8 rows x 8 chunks
  const int vr = lane >> 2, vc = lane & 3;            // V: 16 rows x 4 chunks
  // K row permutation: LDS row p <- global row kp(p) = quad(p)*8 + cg(p)*4 + i(p)
  const int kprow = ((( (w * 8 + r8) & 15) >> 2) * 8) + (((w * 8 + r8) >> 4) * 4) + ((w * 8 + r8) & 3);
  // induction source pointers (advance +2048 / +32 u16 per k-tile)
  const u16* kSrc = Kp + (size_t)kprow * 64 + ((c8 ^ r8) * 8);
  const u16* vSrc = Vtb + (size_t)(w * 16 + vr) * 1536 + ((vc ^ ((vr >> 1) & 3)) * 8);
  u16* const kDst = &kbuf[0][0] + w * 512;   // +2048 for buf1
  u16* const vDst = &vbuf[0][0] + w * 512;

  gll16(kSrc, kDst);
  gll16(vSrc, vDst);

  // Q fragment (rows q = qw0 + l16)
  const u16* qptr = Qp + (size_t)(qw0 + l16) * 64 + quad * 8;
  const bf16x8 qB0 = *(const bf16x8*)qptr;
  const bf16x8 qB1 = *(const bf16x8*)(qptr + 32);

  // qp[q][r] = q . pos_k[r] via MFMA; C layout: row q_loc = quad*4+i, col r = l16
  const f32x4 zf = {0.f, 0.f, 0.f, 0.f};
#pragma unroll
  for (int nf = 0; nf < 9; ++nf) {
    const u16* bp = poskbf + (size_t)(nf * 16 + l16) * 64 + quad * 8;
    bf16x8 b0 = *(const bf16x8*)bp;
    bf16x8 b1 = *(const bf16x8*)(bp + 32);
    f32x4 c = zf;
    c = MFMA16(qB0, b0, c);
    c = MFMA16(qB1, b1, c);
    const int col = nf * 16 + l16;
    if (col < 136) {
#pragma unroll
      for (int i = 0; i < 4; ++i)
        qb_s[(w * 16 + quad * 4 + i) * 136 + col] = f2bf(c[i]);
    }
  }
  __syncthreads();   // qp ready AND buf0 DMA drained

  const float L2E = 1.44269504f;
  const float M8 = -8.0f * L2E;
  const float eLow  = __builtin_fmaf(bf2f(qb_row[0]), L2E, M8);
  const float eHigh = __builtin_fmaf(bf2f(qb_row[128]), L2E, M8);

  f32x4 accf[4];
#pragma unroll
  for (int dc = 0; dc < 4; ++dc) accf[dc] = zf;
  float sSimple = 0.f, sLowSave = 0.f, sDall = 0.f, sD0 = 0.f, sD128 = 0.f;

  const int itLowEnd = (qw0 >= 95) ? (((qw0 - 95) >> 5) + 1) : 0;
  const int itHigh0 = (qw0 + 110) >> 5;
  const int dEnd = itHigh0 < 46 ? itHigh0 : 46;

  const int kswz = (quad ^ (l16 & 7)) * 8;
  const int kswz4 = ((quad + 4) ^ (l16 & 7)) * 8;
  const int vpos = (quad ^ ((l16 >> 1) & 3)) * 8;   // V chunk position after swizzle

  // stage source cursors point at tile it+1
  const u16* kS = kSrc + 2048;
  const u16* vS = vSrc + 32;

  // loop body; kb/vbse/doStage/stageOff are compile-time per call site -> fragment
  // addresses hoist, no runtime buffer select.
  auto body = [&](int it, const u16* kb, const u16* vbse, bool doStage, int stageOff) {
    if (doStage) {
      gll16(kS, kDst + stageOff);
      gll16(vS, vDst + stageOff);
      kS += 2048; vS += 32;
    }

    if (it == itLowEnd) sLowSave = sSimple;
    const int phase = (it < itLowEnd) ? 0 : ((it >= 46) ? 1 : ((it < dEnd) ? 1 : 2));

    // K fragments (row-permuted + chunk-swizzled, conflict-free)
    bf16x8 ka00 = *(const bf16x8*)(kb + l16 * 64 + kswz);
    bf16x8 ka01 = *(const bf16x8*)(kb + l16 * 64 + kswz4);
    bf16x8 ka10 = *(const bf16x8*)(kb + (16 + l16) * 64 + kswz);
    bf16x8 ka11 = *(const bf16x8*)(kb + (16 + l16) * 64 + kswz4);
    // V^T fragments (chunk-swizzled, conflict-free)
    bf16x8 vb0 = *(const bf16x8*)(vbse + l16 * 32 + vpos);
    bf16x8 vb1 = *(const bf16x8*)(vbse + (16 + l16) * 32 + vpos);
    bf16x8 vb2 = *(const bf16x8*)(vbse + (32 + l16) * 32 + vpos);
    bf16x8 vb3 = *(const bf16x8*)(vbse + (48 + l16) * 32 + vpos);

    // diag bias LDS reads (index-only dependence); permuted k: delta = base + quad*8 + cg*4 + i
    float qb[2][4];
    if (phase == 1) {
      const int base = it * 32 + 64 - qw0 - l16 + quad * 8;
#pragma unroll
      for (int cg = 0; cg < 2; ++cg) {
#pragma unroll
        for (int i = 0; i < 4; ++i) {
          int delta = base + cg * 4 + i;
          delta = delta < 0 ? 0 : (delta > 128 ? 128 : delta);
          qb[cg][i] = bf2f(qb_row[delta]);
        }
      }
    }

    f32x4 cc[2];
    cc[0] = zf; cc[1] = zf;
    cc[0] = MFMA16(ka00, qB0, cc[0]);
    cc[0] = MFMA16(ka01, qB1, cc[0]);
    cc[1] = MFMA16(ka10, qB0, cc[1]);
    cc[1] = MFMA16(ka11, qB1, cc[1]);

    float pvv[2][4];
    if (phase != 1) {
      const float eB = (phase == 0) ? eLow : eHigh;
#pragma unroll
      for (int cg = 0; cg < 2; ++cg) {
#pragma unroll
        for (int i = 0; i < 4; ++i) {
          float p = __builtin_amdgcn_exp2f(__builtin_fmaf(cc[cg][i], L2E, eB));
          sSimple += p; pvv[cg][i] = p;
        }
      }
    } else {
      const int kc0 = it * 32;
#pragma unroll
      for (int cg = 0; cg < 2; ++cg) {
        const int krow0 = kc0 + quad * 8 + cg * 4;            // actual k base (permuted)
        const int dbase = krow0 + 64 - qw0 - l16;
#pragma unroll
        for (int i = 0; i < 4; ++i) {
          int delta = dbase + i;
          delta = delta < 0 ? 0 : (delta > 128 ? 128 : delta);
          const float t = cc[cg][i] + qb[cg][i];
          float p = __builtin_amdgcn_exp2f(__builtin_fmaf(t, L2E, M8));
          if (krow0 + i >= 1500) p = 0.f;
          sDall += p;
          sD0   += (delta == 0)   ? p : 0.f;
          sD128 += (delta == 128) ? p : 0.f;
          pvv[cg][i] = p;
        }
        // packed bf16 P stores into the merged buffer (deltas 1..127 only)
        const uint pk01 = cvt_pk_bf16(pvv[cg][0], pvv[cg][1]);
        const uint pk23 = cvt_pk_bf16(pvv[cg][2], pvv[cg][3]);
        const u16 hb[4] = {(u16)pk01, (u16)(pk01 >> 16), (u16)pk23, (u16)(pk23 >> 16)};
#pragma unroll
        for (int i = 0; i < 4; ++i) {
          int delta = dbase + i;
          delta = delta < 0 ? 0 : (delta > 128 ? 128 : delta);
          if ((delta != 0) & (delta != 128)) qb_row[delta] = hb[i];
        }
      }
    }

    // P already in A-fragment order (k = quad*8 + cg*4 + i): just pack to bf16
    union { uint u[4]; bf16x8 v; } pa;
    pa.u[0] = cvt_pk_bf16(pvv[0][0], pvv[0][1]);
    pa.u[1] = cvt_pk_bf16(pvv[0][2], pvv[0][3]);
    pa.u[2] = cvt_pk_bf16(pvv[1][0], pvv[1][1]);
    pa.u[3] = cvt_pk_bf16(pvv[1][2], pvv[1][3]);

    accf[0] = MFMA16(pa.v, vb0, accf[0]);
    accf[1] = MFMA16(pa.v, vb1, accf[1]);
    accf[2] = MFMA16(pa.v, vb2, accf[2]);
    accf[3] = MFMA16(pa.v, vb3, accf[3]);

    __syncthreads();   // drains next-buffer DMA; guards buffer turnover
  };

#pragma unroll 1
  for (int pr = 0; pr < 23; ++pr) {
    const int it0 = pr * 2;
    body(it0,     &kbuf[0][0], &vbuf[0][0], true, 2048);   // cur=0, stage -> buf1
    body(it0 + 1, &kbuf[1][0], &vbuf[1][0], true, 0);      // cur=1, stage -> buf0
  }
  body(46, &kbuf[0][0], &vbuf[0][0], false, 0);

  // reduce softmax state over the 4 quads (q = l16 per lane)
  const float sLow = sLowSave;
  const float sHigh = sSimple - sLowSave;
  float lpart = sSimple + sDall;
  float clow = sLow + sD0;
  float chigh = sHigh + sD128;
#pragma unroll
  for (int m = 16; m <= 32; m <<= 1) {
    lpart += __shfl_xor(lpart, m);
    clow  += __shfl_xor(clow, m);
    chigh += __shfl_xor(chigh, m);
  }
  const float linv = 1.0f / lpart;

  // merged-buffer fixup (wave-private): zero slots the diag pass never wrote so the
  // o2 MFMA sees P=0 there. Row qg: visited slots = [64-qg, 1563-qg] ∩ [1,127];
  // slot 0 always holds qp[0] and must be zeroed. Middle q-tiles: no loop work.
  {
    const int qg_row = qw0 + l16;
    if (quad == 0) qb_row[0] = 0;
    const int lim = 64 - qg_row;              // zero d in [1, lim)
    for (int d = 1 + quad; d < lim; d += 4) qb_row[d] = 0;
    const int dlo = 1564 - qg_row;            // zero d in [dlo, 127]
    for (int d = dlo + quad; d <= 127; d += 4) qb_row[d] = 0;
  }

  // o2 = P[16x128] @ pos_v[128x64] via MFMA (rows wave-private; no barrier needed)
  f32x4 o2[4];
#pragma unroll
  for (int dc = 0; dc < 4; ++dc) o2[dc] = zf;
#pragma unroll
  for (int kk = 0; kk < 4; ++kk) {
    bf16x8 pa2 = *(const bf16x8*)(qb_row + kk * 32 + quad * 8);
#pragma unroll
    for (int dc = 0; dc < 4; ++dc) {
      bf16x8 vb2r = *(const bf16x8*)(posvT + (size_t)(dc * 16 + l16) * 136 + kk * 32 + quad * 8);
      o2[dc] = MFMA16(pa2, vb2r, o2[dc]);
    }
  }

  // per-q scalars live at lane l16=q_loc after butterfly -> shfl from lane q_loc
  float li[4], cl[4], ch[4];
#pragma unroll
  for (int i = 0; i < 4; ++i) {
    const int srcl = quad * 4 + i;
    li[i] = __shfl(linv, srcl);
    cl[i] = __shfl(clow, srcl);
    ch[i] = __shfl(chigh, srcl);
  }

#pragma unroll
  for (int dc = 0; dc < 4; ++dc) {
    const int d = dc * 16 + l16;
    const float pv0 = posv[d], pv1 = posv[128 * 64 + d];
#pragma unroll
    for (int i = 0; i < 4; ++i) {
      const int qg = qw0 + quad * 4 + i;
      if (qg < 1500) {
        const float val = (accf[dc][i] + o2[dc][i] + cl[i] * pv0 + ch[i] * pv1) * li[i];
        hidden[((size_t)(b * 1500 + qg)) * 1024 + (bh & 15) * 64 + d] = f2bf(val);
      }
    }
  }
}

// ---------------- launcher ----------------
extern "C" void kernel_launch(void* const* d_in, const int* in_sizes, int n_in,
                              void* d_out, int out_size, void* d_ws, size_t ws_size,
                              hipStream_t stream) {
  const float* query = (const float*)d_in[0];
  const float* key   = (const float*)d_in[1];
  const float* value = (const float*)d_in[2];
  const float* Wq = (const float*)d_in[3];
  const float* bq = (const float*)d_in[4];
  const float* Wk = (const float*)d_in[5];
  const float* bk = (const float*)d_in[6];
  const float* Wv = (const float*)d_in[7];
  const float* bv = (const float*)d_in[8];
  const float* posk = (const float*)d_in[9];
  const float* posv = (const float*)d_in[10];
  const float* Wfc = (const float*)d_in[11];
  const float* bfc = (const float*)d_in[12];
  float* out = (float*)d_out;

  char* p = (char*)d_ws;
  u16* X = (u16*)p;        p += 3UL * 6016 * 1024 * 2;   // Xq,Xk,Xv (M padded to 6016)
  u16* Wt = (u16*)p;       p += 3UL * 1024 * 1024 * 2;   // Wq_t,Wk_t,Wv_t
  u16* Wfct = (u16*)p;     p += 1024UL * 1024 * 2;
  u16* poskbf = (u16*)p;   p += 144UL * 64 * 2;
  u16* posvT = (u16*)p;    p += 64UL * 136 * 2;
  float* biascat = (float*)p; p += 3UL * 1024 * 4;
  u16* qkv = (u16*)p;      p += 3UL * 4 * 16 * 1536 * 64 * 2;  // q,k,v [B*NH][1536][64]
  u16* hidden = X;                       // X region dead after QKV GEMM
  u16* Vt = X + 6291456;                 // aliases Xk/Xv region, dead after QKV GEMM

  pack_x_kernel<<<dim3(6000, 1, 3), 256, 0, stream>>>(query, key, value, X);
  pack_w_kernel<<<dim3(1025), 256, 0, stream>>>(Wq, Wk, Wv, Wfc, bq, bk, bv, posk, posv,
                                                Wt, Wfct, biascat, poskbf, posvT);

  gemm_bt_kernel<<<dim3(8, 47, 3), 256, 0, stream>>>(
      X, 6016L * 1024, Wt, 1024L * 1024, biascat, 1024L, qkv, nullptr, 0);

  vtrans_kernel<<<dim3(1536), 256, 0, stream>>>(qkv, Vt);

  attn_kernel<<<dim3(1536), 256, 0, stream>>>(qkv, Vt, poskbf, posvT, posv, hidden);

  gemm_bt_kernel<<<dim3(8, 47, 1), 256, 0, stream>>>(
      hidden, 0L, Wfct, 0L, bfc, 0L, nullptr, out, 1);
}

// Round 8
// 348.406 us; speedup vs baseline: 1.0160x; 1.0160x over previous
//
#include <hip/hip_runtime.h>
#include <stdint.h>

typedef unsigned short u16;
typedef __attribute__((ext_vector_type(8))) short bf16x8;
typedef __attribute__((ext_vector_type(4))) float f32x4;

#define MFMA16(a, b, c) __builtin_amdgcn_mfma_f32_16x16x32_bf16(a, b, c, 0, 0, 0)

__device__ __forceinline__ u16 f2bf(float x) {
  union { float f; uint32_t u; } v; v.f = x;
  uint32_t r = (v.u + 0x7FFFu + ((v.u >> 16) & 1u)) >> 16;
  return (u16)r;
}
__device__ __forceinline__ float bf2f(u16 h) {
  union { uint32_t u; float f; } v; v.u = ((uint32_t)h) << 16; return v.f;
}
// packed RNE f32x2 -> bf16x2 (gfx942+ VOP3; low16 = a, high16 = b)
__device__ __forceinline__ uint cvt_pk_bf16(float a, float b) {
  uint r;
  asm("v_cvt_pk_bf16_f32 %0, %1, %2" : "=v"(r) : "v"(a), "v"(b));
  return r;
}
__device__ __forceinline__ void gll16(const void* g, void* s) {
  __builtin_amdgcn_global_load_lds((const __attribute__((address_space(1))) unsigned int*)g,
                                   (__attribute__((address_space(3))) unsigned int*)s, 16, 0, 0);
}

// ---------------- pack kernels ----------------

// merged weight/misc pack, grid 1025 blocks:
//  [0,768):    Wt[z][(n*64+d)*1024 + h] = W[z][n][h][d]
//  [768,1024): Wfct[o*1024 + i] = Wfc[i*1024 + o]
//  1024:       bias concat + pos_k bf16 (144 rows) + pos_v^T bf16 (64x136)
__global__ __launch_bounds__(256) void pack_w_kernel(const float* __restrict__ Wq,
                                                     const float* __restrict__ Wk,
                                                     const float* __restrict__ Wv,
                                                     const float* __restrict__ Wfc,
                                                     const float* __restrict__ bq,
                                                     const float* __restrict__ bk,
                                                     const float* __restrict__ bv,
                                                     const float* __restrict__ posk,
                                                     const float* __restrict__ posv,
                                                     u16* __restrict__ Wt,
                                                     u16* __restrict__ Wfct,
                                                     float* __restrict__ biascat,
                                                     u16* __restrict__ poskbf,
                                                     u16* __restrict__ posvT) {
  __shared__ float tile[64][65];
  const int bi = blockIdx.x;
  if (bi == 1024) {
    for (int i = threadIdx.x; i < 1024; i += 256) {
      biascat[i] = bq[i]; biascat[1024 + i] = bk[i]; biascat[2048 + i] = bv[i];
    }
    for (int i = threadIdx.x; i < 144 * 64; i += 256) {
      int r = i >> 6;
      poskbf[i] = (r < 129) ? f2bf(posk[i]) : (u16)0;
    }
    const int d = threadIdx.x & 63, rr = threadIdx.x >> 6;
#pragma unroll
    for (int j = 0; j < 34; ++j) {
      const int r = rr * 34 + j;
      posvT[d * 136 + r] = (r < 129) ? f2bf(posv[(size_t)r * 64 + d]) : (u16)0;
    }
    return;
  }
  const int r = threadIdx.x >> 2, c0 = (threadIdx.x & 3) * 16;
  const float* src;
  u16* outp;
  if (bi < 768) {
    const int z = bi >> 8, rem = bi & 255, n = rem >> 4, h0 = (rem & 15) * 64;
    const float* W = z == 0 ? Wq : (z == 1 ? Wk : Wv);
    src = W + (size_t)n * 65536 + (size_t)(h0 + r) * 64 + c0;
    outp = Wt + (size_t)z * (1024UL * 1024UL) + (size_t)(n * 64 + r) * 1024 + h0 + c0;
  } else {
    const int t = bi - 768;
    const int i0 = (t & 15) * 64, o0 = (t >> 4) * 64;
    src = Wfc + (size_t)(i0 + r) * 1024 + o0 + c0;
    outp = Wfct + (size_t)(o0 + r) * 1024 + i0 + c0;
  }
#pragma unroll
  for (int j = 0; j < 16; j += 4) {
    float4 f = *(const float4*)(src + j);
    tile[r][c0 + j] = f.x; tile[r][c0 + j + 1] = f.y;
    tile[r][c0 + j + 2] = f.z; tile[r][c0 + j + 3] = f.w;
  }
  __syncthreads();
#pragma unroll
  for (int j = 0; j < 16; ++j) outp[j] = f2bf(tile[c0 + j][r]);
}

// ---------------- GEMM v14: fused pack_x + vtrans ----------------
// mode 0 (QKV): A read DIRECTLY from fp32 query/key/value (reg-stage: 4x float4 ->
//   8 cvt_pk -> 2 ds_write_b128 per lane per k-tile); B (Wt bf16) via global_load_lds.
//   z==0/1 write qkv[bh][1536][64] as before; z==2 writes Vt[bh*64+d][1536] DIRECTLY
//   via an LDS-transposed epilogue (T[128][136] aliases the staging LDS, dead by then).
// mode 1 (FC): A = hidden bf16 via global_load_lds (v13 path), fp32 out.
// Sync per iter: vmcnt(0); [mode0: ds_write A; lgkmcnt(0)]; s_barrier; stage(t+1);
//   compute(t).  XCD-bijective swizzle kept (nwg % 8 == 0).
// LDS: union smem[17408] u16 = 34816 B (loop: As 2x4096 + Bs 2x4096; epi: T 128x136).
__global__ __launch_bounds__(256, 4) void gemm_bt_kernel(
    const float* __restrict__ aQ, const float* __restrict__ aK, const float* __restrict__ aV,
    const u16* __restrict__ Ahid,
    const u16* __restrict__ Bbase, long bStride,
    const float* __restrict__ biasBase, long biasStride,
    u16* __restrict__ outBF, u16* __restrict__ VtOut, float* __restrict__ outF, int mode) {
  __shared__ u16 smem[17408];   // As: [buf*4096], Bs: [8192+buf*4096], T: [0..17407]

  // XCD-aware bijective swizzle of the 3D grid (x=8 n-tiles fastest, y=47 m, z)
  const int nwg = 376 * gridDim.z;           // 1128 (qkv) or 376 (fc)
  const int cpx = nwg >> 3;
  const int lid = blockIdx.x + (blockIdx.y << 3) + blockIdx.z * 376;
  const int swz = (lid & 7) * cpx + (lid >> 3);
  const int z = swz / 376;
  const int rem = swz - z * 376;
  const int m0 = (rem >> 3) * 128, n0 = (rem & 7) * 128;

  const u16* Bt = Bbase + (size_t)z * bStride;
  const float* bias = biasBase + (size_t)z * biasStride;
  const int tid = threadIdx.x, w = tid >> 6, lane = tid & 63;
  const int quad = lane >> 4, l16 = lane & 15;
  const int wm = w >> 1, wn = w & 1;
  const int srow = w * 16 + (lane >> 2);
  const int scol = (lane & 3) * 8;

  // B source induction pointers
  const u16* gB0 = Bt + (size_t)(n0 + srow) * 1024 + scol;
  const u16* gB1 = gB0 + 64UL * 1024;
  const int slab = (w * 16) * 32;            // wave's LDS slab offset (u16)

  f32x4 acc[4][4];
  const f32x4 zf = {0.f, 0.f, 0.f, 0.f};
#pragma unroll
  for (int a = 0; a < 4; ++a)
#pragma unroll
    for (int b = 0; b < 4; ++b) acc[a][b] = zf;

  auto gllB = [&](int buf) {
    gll16(gB0, &smem[8192 + buf * 4096 + slab]);
    gll16(gB1, &smem[8192 + buf * 4096 + slab + 64 * 32]);
    gB0 += 32; gB1 += 32;
  };
  auto compute = [&](int buf) {
    bf16x8 af[4], bfr[4];
#pragma unroll
    for (int f = 0; f < 4; ++f) {
      af[f]  = *(const bf16x8*)&smem[buf * 4096 + (wm * 64 + f * 16 + l16) * 32 + quad * 8];
      bfr[f] = *(const bf16x8*)&smem[8192 + buf * 4096 + (wn * 64 + f * 16 + l16) * 32 + quad * 8];
    }
#pragma unroll
    for (int fm = 0; fm < 4; ++fm)
#pragma unroll
      for (int fn = 0; fn < 4; ++fn)
        acc[fm][fn] = MFMA16(af[fm], bfr[fn], acc[fm][fn]);
  };

  if (mode == 0) {
    // ---- fp32 A path (fused pack_x) ----
    const float* srcF = z == 0 ? aQ : (z == 1 ? aK : aV);
    int rowA0 = m0 + srow;        if (rowA0 > 5999) rowA0 = 5999;
    int rowA1 = m0 + 64 + srow;   if (rowA1 > 5999) rowA1 = 5999;
    const float* fA0 = srcF + (size_t)rowA0 * 1024 + scol;
    const float* fA1 = srcF + (size_t)rowA1 * 1024 + scol;
    float4 a00, a01, a10, a11;
    auto loadA = [&]() {
      a00 = *(const float4*)fA0; a01 = *(const float4*)(fA0 + 4);
      a10 = *(const float4*)fA1; a11 = *(const float4*)(fA1 + 4);
      fA0 += 32; fA1 += 32;
    };
    const int adst = (w * 16 + (lane >> 2)) * 32 + (lane & 3) * 8;
    auto dswriteA = [&](int buf) {
      uint4 lo, hi;
      lo.x = cvt_pk_bf16(a00.x, a00.y); lo.y = cvt_pk_bf16(a00.z, a00.w);
      lo.z = cvt_pk_bf16(a01.x, a01.y); lo.w = cvt_pk_bf16(a01.z, a01.w);
      hi.x = cvt_pk_bf16(a10.x, a10.y); hi.y = cvt_pk_bf16(a10.z, a10.w);
      hi.z = cvt_pk_bf16(a11.x, a11.y); hi.w = cvt_pk_bf16(a11.z, a11.w);
      *(uint4*)&smem[buf * 4096 + adst] = lo;
      *(uint4*)&smem[buf * 4096 + adst + 64 * 32] = hi;
    };

    loadA();          // tile 0 -> regs
    gllB(0);          // tile 0 B -> buf0

#define QKV_SYNC(BUF) do {                                    \
      asm volatile("s_waitcnt vmcnt(0)" ::: "memory");        \
      __builtin_amdgcn_sched_barrier(0);                      \
      dswriteA(BUF);                                          \
      asm volatile("s_waitcnt lgkmcnt(0)" ::: "memory");      \
      __builtin_amdgcn_sched_barrier(0);                      \
      __builtin_amdgcn_s_barrier();                           \
      __builtin_amdgcn_sched_barrier(0);                      \
    } while (0)

#pragma unroll 1
    for (int pr = 0; pr < 16; ++pr) {
      QKV_SYNC(0);
      loadA(); gllB(1);          // tile 2pr+1
      compute(0);
      QKV_SYNC(1);
      if (pr < 15) { loadA(); gllB(0); }   // tile 2pr+2
      compute(1);
    }
#undef QKV_SYNC

    if (z < 2) {
      const float scale = (z == 0) ? 0.125f : 1.0f;
      u16* out = outBF + (size_t)z * (4UL * 16 * 1536 * 64);
#pragma unroll
      for (int fm = 0; fm < 4; ++fm) {
#pragma unroll
        for (int i = 0; i < 4; ++i) {
          const int m = m0 + wm * 64 + fm * 16 + quad * 4 + i;
          if (m >= 6000) continue;
          const int bb = m / 1500;
          const int s = m - bb * 1500;
#pragma unroll
          for (int fn = 0; fn < 4; ++fn) {
            const int n = n0 + wn * 64 + fn * 16 + l16;
            const float vv = (acc[fm][fn][i] + bias[n]) * scale;
            const int h = n >> 6, d = n & 63;
            out[((size_t)(bb * 16 + h) * 1536 + s) * 64 + d] = f2bf(vv);
          }
        }
      }
    } else {
      // ---- fused vtrans: write Vt[(bb*16+h)*64+d][1536] via LDS transpose ----
      __syncthreads();   // all waves done with staging LDS
      u16* T = smem;     // [128][136] u16: T[n_local][m_local]
#pragma unroll
      for (int fm = 0; fm < 4; ++fm) {
        const int ml = wm * 64 + fm * 16 + quad * 4;
#pragma unroll
        for (int fn = 0; fn < 4; ++fn) {
          const int nl = wn * 64 + fn * 16 + l16;
          const float b0 = bias[n0 + nl];
          uint2 pk;
          pk.x = cvt_pk_bf16(acc[fm][fn][0] + b0, acc[fm][fn][1] + b0);
          pk.y = cvt_pk_bf16(acc[fm][fn][2] + b0, acc[fm][fn][3] + b0);
          *(uint2*)&T[nl * 136 + ml] = pk;
        }
      }
      __syncthreads();
#pragma unroll 1
      for (int ps = 0; ps < 8; ++ps) {
        const int row = ps * 16 + (tid >> 4);     // n_local
        const int col = (tid & 15) * 8;           // m_local base
        const int ng = n0 + row;
        const int h = ng >> 6, d = ng & 63;
        const int mg = m0 + col;
        uint4 v = *(const uint4*)&T[row * 136 + col];
        const int bb0 = mg / 1500, bb7 = (mg + 7) / 1500;
        if ((bb0 == bb7) & (mg + 7 < 6000)) {
          u16* dst = VtOut + ((size_t)((bb0 * 16 + h) * 64 + d)) * 1536 + (mg - bb0 * 1500);
          uint2 loh; loh.x = v.x; loh.y = v.y;
          uint2 hih; hih.x = v.z; hih.y = v.w;
          *(uint2*)dst = loh;
          *(uint2*)(dst + 4) = hih;
        } else {
          const u16* tv = (const u16*)&v;
#pragma unroll
          for (int j = 0; j < 8; ++j) {
            const int m = mg + j;
            if (m < 6000) {
              const int bb = m / 1500;
              VtOut[((size_t)((bb * 16 + h) * 64 + d)) * 1536 + (m - bb * 1500)] = tv[j];
            }
          }
        }
      }
    }
  } else {
    // ---- mode 1 (FC): bf16 A via DMA (v13 path) ----
    const u16* gA0 = Ahid + (size_t)(m0 + srow) * 1024 + scol;
    const u16* gA1 = gA0 + 64UL * 1024;
    auto stage1 = [&](int buf) {
      gll16(gA0, &smem[buf * 4096 + slab]);
      gll16(gA1, &smem[buf * 4096 + slab + 64 * 32]);
      gA0 += 32; gA1 += 32;
      gllB(buf);
    };
    stage1(0);
#define FC_SYNC() do {                                        \
      asm volatile("s_waitcnt vmcnt(0)" ::: "memory");        \
      __builtin_amdgcn_sched_barrier(0);                      \
      __builtin_amdgcn_s_barrier();                           \
      __builtin_amdgcn_sched_barrier(0);                      \
    } while (0)
#pragma unroll 1
    for (int pr = 0; pr < 16; ++pr) {
      FC_SYNC();
      stage1(1);
      compute(0);
      FC_SYNC();
      if (pr < 15) stage1(0);
      compute(1);
    }
#undef FC_SYNC
#pragma unroll
    for (int fm = 0; fm < 4; ++fm) {
#pragma unroll
      for (int i = 0; i < 4; ++i) {
        const int m = m0 + wm * 64 + fm * 16 + quad * 4 + i;
        if (m >= 6000) continue;
#pragma unroll
        for (int fn = 0; fn < 4; ++fn) {
          const int n = n0 + wn * 64 + fn * 16 + l16;
          outF[(size_t)m * 1024 + n] = acc[fm][fn][i] + bias[n];
        }
      }
    }
  }
}

// ---------------- fused attention v12 (unchanged, 89.6 us) ----------------
__global__ __launch_bounds__(256, 4) void attn_kernel(const u16* __restrict__ qkv,
                                                      const u16* __restrict__ Vt,
                                                      const u16* __restrict__ poskbf,
                                                      const u16* __restrict__ posvT,
                                                      const float* __restrict__ posv,
                                                      u16* __restrict__ hidden) {
  const size_t ZS = 4UL * 16 * 1536 * 64;
  __shared__ u16 qb_s[64 * 136];    // merged: qp[q][r] (prologue) -> P histogram [q][delta]
  __shared__ u16 kbuf[2][2048];     // K tile 32 rows x 64 d (row-permuted + chunk-swizzled), dbuf
  __shared__ u16 vbuf[2][2048];     // V^T tile 64 d x 32 k (chunk-swizzled), dbuf

  const int tid = threadIdx.x;
  const int w = tid >> 6, lane = tid & 63, quad = lane >> 4, l16 = lane & 15;
  const int bi = blockIdx.x;
  const int bh = bi & 63;
  const int q0 = (bi >> 6) * 64, qw0 = q0 + w * 16;
  const int b = bh >> 4;
  const size_t sb = (size_t)bh * (1536UL * 64UL);
  const u16* Qp = qkv + sb;
  const u16* Kp = qkv + ZS + sb;
  const u16* Vtb = Vt + (size_t)bh * (64UL * 1536UL);
  u16* qb_row = qb_s + (w * 16 + l16) * 136;   // this lane's row (q = qw0 + l16)

  // staging: wave-uniform LDS base + lane*16B (gll16 contract)
  const int r8 = lane >> 3, c8 = lane & 7;            // K: 8 rows x 8 chunks
  const int vr = lane >> 2, vc = lane & 3;            // V: 16 rows x 4 chunks
  // K row permutation: LDS row p <- global row kp(p) = quad(p)*8 + cg(p)*4 + i(p)
  const int kprow = ((( (w * 8 + r8) & 15) >> 2) * 8) + (((w * 8 + r8) >> 4) * 4) + ((w * 8 + r8) & 3);
  // induction source pointers (advance +2048 / +32 u16 per k-tile)
  const u16* kSrc = Kp + (size_t)kprow * 64 + ((c8 ^ r8) * 8);
  const u16* vSrc = Vtb + (size_t)(w * 16 + vr) * 1536 + ((vc ^ ((vr >> 1) & 3)) * 8);
  u16* const kDst = &kbuf[0][0] + w * 512;   // +2048 for buf1
  u16* const vDst = &vbuf[0][0] + w * 512;

  gll16(kSrc, kDst);
  gll16(vSrc, vDst);

  // Q fragment (rows q = qw0 + l16)
  const u16* qptr = Qp + (size_t)(qw0 + l16) * 64 + quad * 8;
  const bf16x8 qB0 = *(const bf16x8*)qptr;
  const bf16x8 qB1 = *(const bf16x8*)(qptr + 32);

  // qp[q][r] = q . pos_k[r] via MFMA; C layout: row q_loc = quad*4+i, col r = l16
  const f32x4 zf = {0.f, 0.f, 0.f, 0.f};
#pragma unroll
  for (int nf = 0; nf < 9; ++nf) {
    const u16* bp = poskbf + (size_t)(nf * 16 + l16) * 64 + quad * 8;
    bf16x8 b0 = *(const bf16x8*)bp;
    bf16x8 b1 = *(const bf16x8*)(bp + 32);
    f32x4 c = zf;
    c = MFMA16(qB0, b0, c);
    c = MFMA16(qB1, b1, c);
    const int col = nf * 16 + l16;
    if (col < 136) {
#pragma unroll
      for (int i = 0; i < 4; ++i)
        qb_s[(w * 16 + quad * 4 + i) * 136 + col] = f2bf(c[i]);
    }
  }
  __syncthreads();   // qp ready AND buf0 DMA drained

  const float L2E = 1.44269504f;
  const float M8 = -8.0f * L2E;
  const float eLow  = __builtin_fmaf(bf2f(qb_row[0]), L2E, M8);
  const float eHigh = __builtin_fmaf(bf2f(qb_row[128]), L2E, M8);

  f32x4 accf[4];
#pragma unroll
  for (int dc = 0; dc < 4; ++dc) accf[dc] = zf;
  float sSimple = 0.f, sLowSave = 0.f, sDall = 0.f, sD0 = 0.f, sD128 = 0.f;

  const int itLowEnd = (qw0 >= 95) ? (((qw0 - 95) >> 5) + 1) : 0;
  const int itHigh0 = (qw0 + 110) >> 5;
  const int dEnd = itHigh0 < 46 ? itHigh0 : 46;

  const int kswz = (quad ^ (l16 & 7)) * 8;
  const int kswz4 = ((quad + 4) ^ (l16 & 7)) * 8;
  const int vpos = (quad ^ ((l16 >> 1) & 3)) * 8;   // V chunk position after swizzle

  // stage source cursors point at tile it+1
  const u16* kS = kSrc + 2048;
  const u16* vS = vSrc + 32;

  // loop body; kb/vbse/doStage/stageOff are compile-time per call site -> fragment
  // addresses hoist, no runtime buffer select.
  auto body = [&](int it, const u16* kb, const u16* vbse, bool doStage, int stageOff) {
    if (doStage) {
      gll16(kS, kDst + stageOff);
      gll16(vS, vDst + stageOff);
      kS += 2048; vS += 32;
    }

    if (it == itLowEnd) sLowSave = sSimple;
    const int phase = (it < itLowEnd) ? 0 : ((it >= 46) ? 1 : ((it < dEnd) ? 1 : 2));

    // K fragments (row-permuted + chunk-swizzled, conflict-free)
    bf16x8 ka00 = *(const bf16x8*)(kb + l16 * 64 + kswz);
    bf16x8 ka01 = *(const bf16x8*)(kb + l16 * 64 + kswz4);
    bf16x8 ka10 = *(const bf16x8*)(kb + (16 + l16) * 64 + kswz);
    bf16x8 ka11 = *(const bf16x8*)(kb + (16 + l16) * 64 + kswz4);
    // V^T fragments (chunk-swizzled, conflict-free)
    bf16x8 vb0 = *(const bf16x8*)(vbse + l16 * 32 + vpos);
    bf16x8 vb1 = *(const bf16x8*)(vbse + (16 + l16) * 32 + vpos);
    bf16x8 vb2 = *(const bf16x8*)(vbse + (32 + l16) * 32 + vpos);
    bf16x8 vb3 = *(const bf16x8*)(vbse + (48 + l16) * 32 + vpos);

    // diag bias LDS reads (index-only dependence); permuted k: delta = base + quad*8 + cg*4 + i
    float qb[2][4];
    if (phase == 1) {
      const int base = it * 32 + 64 - qw0 - l16 + quad * 8;
#pragma unroll
      for (int cg = 0; cg < 2; ++cg) {
#pragma unroll
        for (int i = 0; i < 4; ++i) {
          int delta = base + cg * 4 + i;
          delta = delta < 0 ? 0 : (delta > 128 ? 128 : delta);
          qb[cg][i] = bf2f(qb_row[delta]);
        }
      }
    }

    f32x4 cc[2];
    cc[0] = zf; cc[1] = zf;
    cc[0] = MFMA16(ka00, qB0, cc[0]);
    cc[0] = MFMA16(ka01, qB1, cc[0]);
    cc[1] = MFMA16(ka10, qB0, cc[1]);
    cc[1] = MFMA16(ka11, qB1, cc[1]);

    float pvv[2][4];
    if (phase != 1) {
      const float eB = (phase == 0) ? eLow : eHigh;
#pragma unroll
      for (int cg = 0; cg < 2; ++cg) {
#pragma unroll
        for (int i = 0; i < 4; ++i) {
          float p = __builtin_amdgcn_exp2f(__builtin_fmaf(cc[cg][i], L2E, eB));
          sSimple += p; pvv[cg][i] = p;
        }
      }
    } else {
      const int kc0 = it * 32;
#pragma unroll
      for (int cg = 0; cg < 2; ++cg) {
        const int krow0 = kc0 + quad * 8 + cg * 4;            // actual k base (permuted)
        const int dbase = krow0 + 64 - qw0 - l16;
#pragma unroll
        for (int i = 0; i < 4; ++i) {
          int delta = dbase + i;
          delta = delta < 0 ? 0 : (delta > 128 ? 128 : delta);
          const float t = cc[cg][i] + qb[cg][i];
          float p = __builtin_amdgcn_exp2f(__builtin_fmaf(t, L2E, M8));
          if (krow0 + i >= 1500) p = 0.f;
          sDall += p;
          sD0   += (delta == 0)   ? p : 0.f;
          sD128 += (delta == 128) ? p : 0.f;
          pvv[cg][i] = p;
        }
        // packed bf16 P stores into the merged buffer (deltas 1..127 only)
        const uint pk01 = cvt_pk_bf16(pvv[cg][0], pvv[cg][1]);
        const uint pk23 = cvt_pk_bf16(pvv[cg][2], pvv[cg][3]);
        const u16 hb[4] = {(u16)pk01, (u16)(pk01 >> 16), (u16)pk23, (u16)(pk23 >> 16)};
#pragma unroll
        for (int i = 0; i < 4; ++i) {
          int delta = dbase + i;
          delta = delta < 0 ? 0 : (delta > 128 ? 128 : delta);
          if ((delta != 0) & (delta != 128)) qb_row[delta] = hb[i];
        }
      }
    }

    // P already in A-fragment order (k = quad*8 + cg*4 + i): just pack to bf16
    union { uint u[4]; bf16x8 v; } pa;
    pa.u[0] = cvt_pk_bf16(pvv[0][0], pvv[0][1]);
    pa.u[1] = cvt_pk_bf16(pvv[0][2], pvv[0][3]);
    pa.u[2] = cvt_pk_bf16(pvv[1][0], pvv[1][1]);
    pa.u[3] = cvt_pk_bf16(pvv[1][2], pvv[1][3]);

    accf[0] = MFMA16(pa.v, vb0, accf[0]);
    accf[1] = MFMA16(pa.v, vb1, accf[1]);
    accf[2] = MFMA16(pa.v, vb2, accf[2]);
    accf[3] = MFMA16(pa.v, vb3, accf[3]);

    __syncthreads();   // drains next-buffer DMA; guards buffer turnover
  };

#pragma unroll 1
  for (int pr = 0; pr < 23; ++pr) {
    const int it0 = pr * 2;
    body(it0,     &kbuf[0][0], &vbuf[0][0], true, 2048);   // cur=0, stage -> buf1
    body(it0 + 1, &kbuf[1][0], &vbuf[1][0], true, 0);      // cur=1, stage -> buf0
  }
  body(46, &kbuf[0][0], &vbuf[0][0], false, 0);

  // reduce softmax state over the 4 quads (q = l16 per lane)
  const float sLow = sLowSave;
  const float sHigh = sSimple - sLowSave;
  float lpart = sSimple + sDall;
  float clow = sLow + sD0;
  float chigh = sHigh + sD128;
#pragma unroll
  for (int m = 16; m <= 32; m <<= 1) {
    lpart += __shfl_xor(lpart, m);
    clow  += __shfl_xor(clow, m);
    chigh += __shfl_xor(chigh, m);
  }
  const float linv = 1.0f / lpart;

  // merged-buffer fixup (wave-private): zero slots the diag pass never wrote so the
  // o2 MFMA sees P=0 there. Row qg: visited slots = [64-qg, 1563-qg] ∩ [1,127];
  // slot 0 always holds qp[0] and must be zeroed. Middle q-tiles: no loop work.
  {
    const int qg_row = qw0 + l16;
    if (quad == 0) qb_row[0] = 0;
    const int lim = 64 - qg_row;              // zero d in [1, lim)
    for (int d = 1 + quad; d < lim; d += 4) qb_row[d] = 0;
    const int dlo = 1564 - qg_row;            // zero d in [dlo, 127]
    for (int d = dlo + quad; d <= 127; d += 4) qb_row[d] = 0;
  }

  // o2 = P[16x128] @ pos_v[128x64] via MFMA (rows wave-private; no barrier needed)
  f32x4 o2[4];
#pragma unroll
  for (int dc = 0; dc < 4; ++dc) o2[dc] = zf;
#pragma unroll
  for (int kk = 0; kk < 4; ++kk) {
    bf16x8 pa2 = *(const bf16x8*)(qb_row + kk * 32 + quad * 8);
#pragma unroll
    for (int dc = 0; dc < 4; ++dc) {
      bf16x8 vb2r = *(const bf16x8*)(posvT + (size_t)(dc * 16 + l16) * 136 + kk * 32 + quad * 8);
      o2[dc] = MFMA16(pa2, vb2r, o2[dc]);
    }
  }

  // per-q scalars live at lane l16=q_loc after butterfly -> shfl from lane q_loc
  float li[4], cl[4], ch[4];
#pragma unroll
  for (int i = 0; i < 4; ++i) {
    const int srcl = quad * 4 + i;
    li[i] = __shfl(linv, srcl);
    cl[i] = __shfl(clow, srcl);
    ch[i] = __shfl(chigh, srcl);
  }

#pragma unroll
  for (int dc = 0; dc < 4; ++dc) {
    const int d = dc * 16 + l16;
    const float pv0 = posv[d], pv1 = posv[128 * 64 + d];
#pragma unroll
    for (int i = 0; i < 4; ++i) {
      const int qg = qw0 + quad * 4 + i;
      if (qg < 1500) {
        const float val = (accf[dc][i] + o2[dc][i] + cl[i] * pv0 + ch[i] * pv1) * li[i];
        hidden[((size_t)(b * 1500 + qg)) * 1024 + (bh & 15) * 64 + d] = f2bf(val);
      }
    }
  }
}

// ---------------- launcher ----------------
extern "C" void kernel_launch(void* const* d_in, const int* in_sizes, int n_in,
                              void* d_out, int out_size, void* d_ws, size_t ws_size,
                              hipStream_t stream) {
  const float* query = (const float*)d_in[0];
  const float* key   = (const float*)d_in[1];
  const float* value = (const float*)d_in[2];
  const float* Wq = (const float*)d_in[3];
  const float* bq = (const float*)d_in[4];
  const float* Wk = (const float*)d_in[5];
  const float* bk = (const float*)d_in[6];
  const float* Wv = (const float*)d_in[7];
  const float* bv = (const float*)d_in[8];
  const float* posk = (const float*)d_in[9];
  const float* posv = (const float*)d_in[10];
  const float* Wfc = (const float*)d_in[11];
  const float* bfc = (const float*)d_in[12];
  float* out = (float*)d_out;

  char* p = (char*)d_ws;
  u16* X = (u16*)p;        p += 3UL * 6016 * 1024 * 2;   // hidden + Vt live here (X staging gone)
  u16* Wt = (u16*)p;       p += 3UL * 1024 * 1024 * 2;   // Wq_t,Wk_t,Wv_t
  u16* Wfct = (u16*)p;     p += 1024UL * 1024 * 2;
  u16* poskbf = (u16*)p;   p += 144UL * 64 * 2;
  u16* posvT = (u16*)p;    p += 64UL * 136 * 2;
  float* biascat = (float*)p; p += 3UL * 1024 * 4;
  u16* qkv = (u16*)p;      p += 3UL * 4 * 16 * 1536 * 64 * 2;  // q,k slabs used (v slab idle)
  u16* hidden = X;                       // [6016][1024] bf16
  u16* Vt = X + 6291456;                 // [64*64][1536] bf16

  pack_w_kernel<<<dim3(1025), 256, 0, stream>>>(Wq, Wk, Wv, Wfc, bq, bk, bv, posk, posv,
                                                Wt, Wfct, biascat, poskbf, posvT);

  gemm_bt_kernel<<<dim3(8, 47, 3), 256, 0, stream>>>(
      query, key, value, nullptr, Wt, 1024L * 1024, biascat, 1024L, qkv, Vt, nullptr, 0);

  attn_kernel<<<dim3(1536), 256, 0, stream>>>(qkv, Vt, poskbf, posvT, posv, hidden);

  gemm_bt_kernel<<<dim3(8, 47, 1), 256, 0, stream>>>(
      nullptr, nullptr, nullptr, hidden, Wfct, 0L, bfc, 0L, nullptr, nullptr, out, 1);
}